// Round 6
// baseline (88.124 us; speedup 1.0000x reference)
//
#include <hip/hip_runtime.h>
#include <math.h>

#define NODES 1024
#define BATCH 16
#define TLEN 24
#define LAYERS 24
#define NLANES (NODES * BATCH) /* 16384 */
#define LOG2E 1.44269504088896340736f
#define CPB 20 /* chains per block: 4 waves x 5 rings */

typedef float v2f __attribute__((ext_vector_type(2)));

#if __has_builtin(__builtin_amdgcn_rcpf)
__device__ __forceinline__ float fast_rcp(float x) { return __builtin_amdgcn_rcpf(x); }
#else
__device__ __forceinline__ float fast_rcp(float x) { return 1.0f / x; }
#endif

#if __has_builtin(__builtin_amdgcn_exp2f)
__device__ __forceinline__ float fast_exp2(float x) { return __builtin_amdgcn_exp2f(x); }
#else
__device__ __forceinline__ float fast_exp2(float x) { return exp2f(x); }
#endif

// Packed math via COMPILER vector ops (no inline asm) -> v_pk_* on gfx950.
#if __has_builtin(__builtin_elementwise_fma)
__device__ __forceinline__ v2f pk_fma(v2f a, v2f b, v2f c) {
    return __builtin_elementwise_fma(a, b, c);
}
#else
__device__ __forceinline__ v2f pk_fma(v2f a, v2f b, v2f c) {
    v2f d; d.x = fmaf(a.x, b.x, c.x); d.y = fmaf(a.y, b.y, c.y); return d;
}
#endif

struct GruK {
    v2f rW, rU, rC, zW, zU, zC, nW, nC, nU, nD;
};

// Constants for TWO layers (la -> .x, lb -> .y), pre-scaled by -log2e.
__device__ __forceinline__ GruK make_k2(
    const float* __restrict__ w_ih, const float* __restrict__ w_hh,
    const float* __restrict__ b_ih, const float* __restrict__ b_hh,
    int la, int lb)
{
    GruK K;
    #pragma unroll
    for (int s = 0; s < 2; ++s) {
        const int l = s ? lb : la;
        const float wi0 = w_ih[l*3+0], wi1 = w_ih[l*3+1], wi2 = w_ih[l*3+2];
        const float wh0 = w_hh[l*3+0], wh1 = w_hh[l*3+1], wh2 = w_hh[l*3+2];
        const float bi0 = b_ih[l*3+0], bi1 = b_ih[l*3+1], bi2 = b_ih[l*3+2];
        const float bh0 = b_hh[l*3+0], bh1 = b_hh[l*3+1], bh2 = b_hh[l*3+2];
        K.rW[s] = -LOG2E * wi0; K.rU[s] = -LOG2E * wh0; K.rC[s] = -LOG2E * (bi0 + bh0);
        K.zW[s] = -LOG2E * wi1; K.zU[s] = -LOG2E * wh1; K.zC[s] = -LOG2E * (bi1 + bh1);
        K.nW[s] = -2.0f*LOG2E * wi2; K.nC[s] = -2.0f*LOG2E * bi2;
        K.nU[s] = -2.0f*LOG2E * wh2; K.nD[s] = -2.0f*LOG2E * bh2;
    }
    return K;
}

// One GRU cell, component-wise over the 2 packed layer-slots (bit-identical
// arithmetic to the passing round-4/5 form):
// er/ez/en are e^{-a} forms; r = 1/(1+er);
// h' = (ez*(1-en) + h*(1+en)) / ((1+ez)*(1+en))  -- one final rcp.
__device__ __forceinline__ v2f gru_cell(const GruK& K, v2f h, v2f xin) {
    const v2f ONE = (v2f){1.0f, 1.0f};
    v2f ar = pk_fma(K.rU, h, pk_fma(K.rW, xin, K.rC));
    v2f az = pk_fma(K.zU, h, pk_fma(K.zW, xin, K.zC));
    v2f er; er.x = fast_exp2(ar.x); er.y = fast_exp2(ar.y);
    v2f ez; ez.x = fast_exp2(az.x); ez.y = fast_exp2(az.y);
    v2f er1 = er + ONE;
    v2f r;  r.x = fast_rcp(er1.x); r.y = fast_rcp(er1.y);
    v2f an = pk_fma(r, pk_fma(K.nU, h, K.nD), pk_fma(K.nW, xin, K.nC));
    v2f en; en.x = fast_exp2(an.x); en.y = fast_exp2(an.y);
    v2f num = pk_fma(en, h - ez, h + ez);
    v2f den = (ez + ONE) * (en + ONE);
    v2f rd; rd.x = fast_rcp(den.x); rd.y = fast_rcp(den.y);
    return num * rd;
}

// Ring-pipelined GRU: 12-lane rings, CONSECUTIVE layer pair per lane.
// Lane sl of a ring owns layers (2sl -> h.x, 2sl+1 -> h.y). Cell (p,l,t)
// runs at tick p*24+l+t. Inputs per tick:
//   x-slot (layer 2sl):  prev lane's h.y (layer 2sl-1) from prev tick; for
//                        sl==0 the SAME shfl gives lane11.h.y = layer 23 =
//                        the pass-feedback — no special case in steady.
//   y-slot (layer 2sl+1): own h.x from prev tick (a register, no shfl).
// => exactly ONE bpermute per tick. Wave64 = 5 rings (60 lanes) + 4 idle.
// 3280 waves total = 3.2 waves/SIMD for latency hiding.
__global__ __launch_bounds__(256) void gru_pipe_kernel(
    const float* __restrict__ inputs, const float* __restrict__ w_ih,
    const float* __restrict__ w_hh, const float* __restrict__ b_ih,
    const float* __restrict__ b_hh, const int* __restrict__ horizon_p,
    float* __restrict__ hv, float* __restrict__ h_out)
{
    __shared__ float xl[CPB][TLEN];
    const int tid = threadIdx.x;
    const int wid = tid >> 6;
    const int lane = tid & 63;
    const int r5 = lane / 12;
    const bool vlane = (lane < 60);
    const int ring = vlane ? r5 : 4;          // clamp idle lanes onto ring 4
    const int sl = vlane ? (lane - r5 * 12) : (lane - 60);
    const int c = blockIdx.x * CPB + wid * 5 + ring;
    const bool cvalid = vlane && (c < NLANES);

    const GruK K = make_k2(w_ih, w_hh, b_ih, b_hh, 2 * sl, 2 * sl + 1);

    // Stage the block's chains' input sequences: xl[cl][t] = inputs[b,0,node,t]
    for (int i = tid; i < CPB * TLEN; i += 256) {
        const int cl = i / TLEN, t = i - cl * TLEN;
        const int cc = blockIdx.x * CPB + cl;
        const int node = cc >> 4, b = cc & 15;
        xl[cl][t] = (cc < NLANES)
                  ? inputs[((size_t)b * NODES + node) * TLEN + t] : 0.0f;
    }
    __syncthreads();

    const int H = *horizon_p;
    const int last = H * TLEN;                               // 192 for H=8
    const int ringsrc = vlane
        ? (r5 * 12 + ((sl == 0) ? 11 : (sl - 1)))
        : lane;
    const bool lead = vlane && (sl == 0);
    const float* xrow = &xl[wid * 5 + ring][0];

    v2f h = (v2f){0.0f, 0.0f};

    // Fill: ticks [0, 24). Lead lane's x-slot takes the original input.
    for (int k = 0; k < TLEN; ++k) {
        v2f xin;
        xin.x = __shfl(h.y, ringsrc, 64);
        xin.y = h.x;
        if (lead) xin.x = xrow[k];
        v2f hn = gru_cell(K, h, xin);
        h.x = (k >= 2 * sl)     ? hn.x : h.x;
        h.y = (k >= 2 * sl + 1) ? hn.y : h.y;
    }
    // Steady: ticks [24, last) — every slot active, no masks, one shfl.
    for (int k = TLEN; k < last; ++k) {
        v2f xin;
        xin.x = __shfl(h.y, ringsrc, 64);
        xin.y = h.x;
        h = gru_cell(K, h, xin);
    }
    // Drain: ticks [last, last+23). Slot (2sl+s) finishes at k = 2sl+s+last.
    for (int k = last; k < last + LAYERS - 1; ++k) {
        v2f xin;
        xin.x = __shfl(h.y, ringsrc, 64);
        xin.y = h.x;
        v2f hn = gru_cell(K, h, xin);
        h.x = (k < 2 * sl + last)     ? hn.x : h.x;
        h.y = (k < 2 * sl + 1 + last) ? hn.y : h.y;
    }

    if (cvalid) {
        hv[(size_t)(2 * sl + 0) * NLANES + c] = h.x;
        hv[(size_t)(2 * sl + 1) * NLANES + c] = h.y;
        const int node = c >> 4, b = c & 15;
        float* ho = h_out + (size_t)node * (LAYERS * BATCH) + b;
        ho[(2 * sl + 0) * BATCH] = h.x;
        ho[(2 * sl + 1) * BATCH] = h.y;
    }
}

// adj[l][i][j] = dot_b(hv[l,i,:], hv[l,j,:]) * inv_i * inv_j.
// 64x64 tile per 256-thread block; B tile transposed in LDS (conflict-free).
// Already at the HBM-write floor (~100 MB output).
__global__ __launch_bounds__(256) void adj_kernel(
    const float* __restrict__ hv, float* __restrict__ adj)
{
    const int l = blockIdx.z;
    const int i0 = blockIdx.y * 64;
    const int j0 = blockIdx.x * 64;
    __shared__ float As[64 * 16];   // [row][k]
    __shared__ float Bt[16 * 64];   // [k][col]
    __shared__ float iA[64];
    __shared__ float iB[64];
    const int tid = threadIdx.x;
    const float* hvl = hv + (size_t)l * NLANES;

    ((float4*)As)[tid] = ((const float4*)(hvl + (size_t)i0 * 16))[tid];
    {
        const int j = tid >> 2;
        const int kc = (tid & 3) * 4;
        float4 bv = *(const float4*)(hvl + (size_t)(j0 + j) * 16 + kc);
        Bt[(kc + 0) * 64 + j] = bv.x;
        Bt[(kc + 1) * 64 + j] = bv.y;
        Bt[(kc + 2) * 64 + j] = bv.z;
        Bt[(kc + 3) * 64 + j] = bv.w;
    }
    __syncthreads();

    if (tid < 64) {
        float s = 0.0f;
        #pragma unroll
        for (int k = 0; k < 16; ++k) { float v = As[tid * 16 + k]; s = fmaf(v, v, s); }
        iA[tid] = fast_rcp(fmaxf(sqrtf(s), 1e-8f));
    } else if (tid < 128) {
        const int j = tid - 64;
        float s = 0.0f;
        #pragma unroll
        for (int k = 0; k < 16; ++k) { float v = Bt[k * 64 + j]; s = fmaf(v, v, s); }
        iB[j] = fast_rcp(fmaxf(sqrtf(s), 1e-8f));
    }
    __syncthreads();

    const int ty = tid >> 4;   // row group (4 rows)
    const int tx = tid & 15;   // col group (4 cols = 1 float4)

    float4 acc0 = {0,0,0,0}, acc1 = {0,0,0,0}, acc2 = {0,0,0,0}, acc3 = {0,0,0,0};
    #pragma unroll
    for (int kk = 0; kk < 4; ++kk) {
        float4 a0 = ((const float4*)As)[(ty * 4 + 0) * 4 + kk];
        float4 a1 = ((const float4*)As)[(ty * 4 + 1) * 4 + kk];
        float4 a2 = ((const float4*)As)[(ty * 4 + 2) * 4 + kk];
        float4 a3 = ((const float4*)As)[(ty * 4 + 3) * 4 + kk];
        #pragma unroll
        for (int e = 0; e < 4; ++e) {
            const int k = kk * 4 + e;
            float4 bk = ((const float4*)Bt)[k * 16 + tx];
            const float a0e = (e == 0) ? a0.x : (e == 1) ? a0.y : (e == 2) ? a0.z : a0.w;
            const float a1e = (e == 0) ? a1.x : (e == 1) ? a1.y : (e == 2) ? a1.z : a1.w;
            const float a2e = (e == 0) ? a2.x : (e == 1) ? a2.y : (e == 2) ? a2.z : a2.w;
            const float a3e = (e == 0) ? a3.x : (e == 1) ? a3.y : (e == 2) ? a3.z : a3.w;
            acc0.x = fmaf(a0e, bk.x, acc0.x); acc0.y = fmaf(a0e, bk.y, acc0.y);
            acc0.z = fmaf(a0e, bk.z, acc0.z); acc0.w = fmaf(a0e, bk.w, acc0.w);
            acc1.x = fmaf(a1e, bk.x, acc1.x); acc1.y = fmaf(a1e, bk.y, acc1.y);
            acc1.z = fmaf(a1e, bk.z, acc1.z); acc1.w = fmaf(a1e, bk.w, acc1.w);
            acc2.x = fmaf(a2e, bk.x, acc2.x); acc2.y = fmaf(a2e, bk.y, acc2.y);
            acc2.z = fmaf(a2e, bk.z, acc2.z); acc2.w = fmaf(a2e, bk.w, acc2.w);
            acc3.x = fmaf(a3e, bk.x, acc3.x); acc3.y = fmaf(a3e, bk.y, acc3.y);
            acc3.z = fmaf(a3e, bk.z, acc3.z); acc3.w = fmaf(a3e, bk.w, acc3.w);
        }
    }

    float* out = adj + (size_t)l * NODES * NODES;
    const float4 ib4 = ((const float4*)iB)[tx];
    #pragma unroll
    for (int ii = 0; ii < 4; ++ii) {
        const int i = i0 + ty * 4 + ii;
        const float si = iA[ty * 4 + ii];
        float4 a = (ii == 0) ? acc0 : (ii == 1) ? acc1 : (ii == 2) ? acc2 : acc3;
        float4 w;
        w.x = a.x * si * ib4.x;
        w.y = a.y * si * ib4.y;
        w.z = a.z * si * ib4.z;
        w.w = a.w * si * ib4.w;
        *(float4*)(out + (size_t)i * NODES + j0 + tx * 4) = w;
    }
}

extern "C" void kernel_launch(void* const* d_in, const int* in_sizes, int n_in,
                              void* d_out, int out_size, void* d_ws, size_t ws_size,
                              hipStream_t stream) {
    const float* inputs = (const float*)d_in[0];
    const float* w_ih   = (const float*)d_in[1];
    const float* w_hh   = (const float*)d_in[2];
    const float* b_ih   = (const float*)d_in[3];
    const float* b_hh   = (const float*)d_in[4];
    const int*   horiz  = (const int*)d_in[5];

    float* adj   = (float*)d_out;                                   // [24,1024,1024]
    float* h_out = (float*)d_out + (size_t)LAYERS * NODES * NODES;  // [1024,24,16]
    float* hv    = (float*)d_ws;                                    // [24][16384]

    // ceil(16384/20) = 820 blocks x 4 waves = 3280 waves = 3.2/SIMD
    const int nblk = (NLANES + CPB - 1) / CPB;
    gru_pipe_kernel<<<nblk, 256, 0, stream>>>(inputs, w_ih, w_hh, b_ih, b_hh,
                                              horiz, hv, h_out);

    dim3 grid(NODES / 64, NODES / 64, LAYERS);
    adj_kernel<<<grid, 256, 0, stream>>>(hv, adj);
}

// Round 7
// 80.901 us; speedup vs baseline: 1.0893x; 1.0893x over previous
//
#include <hip/hip_runtime.h>
#include <math.h>

#define NODES 1024
#define BATCH 16
#define TLEN 24
#define LAYERS 24
#define NLANES (NODES * BATCH) /* 16384 */
#define LOG2E 1.44269504088896340736f

typedef float v2f __attribute__((ext_vector_type(2)));

#if __has_builtin(__builtin_amdgcn_rcpf)
__device__ __forceinline__ float fast_rcp(float x) { return __builtin_amdgcn_rcpf(x); }
#else
__device__ __forceinline__ float fast_rcp(float x) { return 1.0f / x; }
#endif

#if __has_builtin(__builtin_amdgcn_exp2f)
__device__ __forceinline__ float fast_exp2(float x) { return __builtin_amdgcn_exp2f(x); }
#else
__device__ __forceinline__ float fast_exp2(float x) { return exp2f(x); }
#endif

// Packed math via COMPILER vector ops (no inline asm) -> v_pk_* on gfx950.
#if __has_builtin(__builtin_elementwise_fma)
__device__ __forceinline__ v2f pk_fma(v2f a, v2f b, v2f c) {
    return __builtin_elementwise_fma(a, b, c);
}
#else
__device__ __forceinline__ v2f pk_fma(v2f a, v2f b, v2f c) {
    v2f d; d.x = fmaf(a.x, b.x, c.x); d.y = fmaf(a.y, b.y, c.y); return d;
}
#endif

struct GruK {
    v2f rW, rU, rC, zW, zU, zC, nW, nC, nU, nD;
};

// Constants for TWO layers (la -> .x, lb -> .y), pre-scaled by -log2e.
__device__ __forceinline__ GruK make_k2(
    const float* __restrict__ w_ih, const float* __restrict__ w_hh,
    const float* __restrict__ b_ih, const float* __restrict__ b_hh,
    int la, int lb)
{
    GruK K;
    #pragma unroll
    for (int s = 0; s < 2; ++s) {
        const int l = s ? lb : la;
        const float wi0 = w_ih[l*3+0], wi1 = w_ih[l*3+1], wi2 = w_ih[l*3+2];
        const float wh0 = w_hh[l*3+0], wh1 = w_hh[l*3+1], wh2 = w_hh[l*3+2];
        const float bi0 = b_ih[l*3+0], bi1 = b_ih[l*3+1], bi2 = b_ih[l*3+2];
        const float bh0 = b_hh[l*3+0], bh1 = b_hh[l*3+1], bh2 = b_hh[l*3+2];
        K.rW[s] = -LOG2E * wi0; K.rU[s] = -LOG2E * wh0; K.rC[s] = -LOG2E * (bi0 + bh0);
        K.zW[s] = -LOG2E * wi1; K.zU[s] = -LOG2E * wh1; K.zC[s] = -LOG2E * (bi1 + bh1);
        K.nW[s] = -2.0f*LOG2E * wi2; K.nC[s] = -2.0f*LOG2E * bi2;
        K.nU[s] = -2.0f*LOG2E * wh2; K.nD[s] = -2.0f*LOG2E * bh2;
    }
    return K;
}

// One GRU cell over 2 packed layer-slots (bit-identical arithmetic to the
// passing round-4/5/6 form): er/ez/en are e^{-a} forms; r = 1/(1+er);
// h' = (ez*(1-en) + h*(1+en)) / ((1+ez)*(1+en))  -- one final rcp.
__device__ __forceinline__ v2f gru_cell(const GruK& K, v2f h, v2f xin) {
    const v2f ONE = (v2f){1.0f, 1.0f};
    v2f ar = pk_fma(K.rU, h, pk_fma(K.rW, xin, K.rC));
    v2f az = pk_fma(K.zU, h, pk_fma(K.zW, xin, K.zC));
    v2f er; er.x = fast_exp2(ar.x); er.y = fast_exp2(ar.y);
    v2f ez; ez.x = fast_exp2(az.x); ez.y = fast_exp2(az.y);
    v2f er1 = er + ONE;
    v2f r;  r.x = fast_rcp(er1.x); r.y = fast_rcp(er1.y);
    v2f an = pk_fma(r, pk_fma(K.nU, h, K.nD), pk_fma(K.nW, xin, K.nC));
    v2f en; en.x = fast_exp2(an.x); en.y = fast_exp2(an.y);
    v2f num = pk_fma(en, h - ez, h + ez);
    v2f den = (ez + ONE) * (en + ONE);
    v2f rd; rd.x = fast_rcp(den.x); rd.y = fast_rcp(den.y);
    return num * rd;
}

// Ring-pipelined GRU: 4-lane rings, 6 CONSECUTIVE layers per lane packed as
// 3 v2f of consecutive layer-pairs. Lane sl owns layers 6sl..6sl+5:
//   h0 = (6sl, 6sl+1), h1 = (6sl+2, 6sl+3), h2 = (6sl+4, 6sl+5).
// Cell (p,l,t) at tick p*24+l+t. Prev-tick inputs per tick:
//   h0.x <- prev lane's h2.y (ONE shfl; pass-wrap 0<-23 is the same shfl),
//   h0.y <- own h0.x, h1.x <- own h0.y, h1.y <- own h1.x,
//   h2.x <- own h1.y, h2.y <- own h2.x        (all registers).
// Wave64 = 16 rings, ALL lanes active: 16 chains/wave, ILP 3 + cross-tick
// SWP via unroll. 1024 waves = 1/SIMD.
__global__ __launch_bounds__(256) void gru_pipe_kernel(
    const float* __restrict__ inputs, const float* __restrict__ w_ih,
    const float* __restrict__ w_hh, const float* __restrict__ b_ih,
    const float* __restrict__ b_hh, const int* __restrict__ horizon_p,
    float* __restrict__ hv, float* __restrict__ h_out)
{
    __shared__ float xl[64][TLEN + 1];   // +1 pad: conflict-free lead reads
    const int tid = threadIdx.x;
    const int wid = tid >> 6;
    const int lane = tid & 63;
    const int ring = lane >> 2;          // 0..15
    const int sl = lane & 3;             // ring-local lane
    const int L0 = 6 * sl;               // first owned layer
    const int chain_local = wid * 16 + ring;
    const int c = blockIdx.x * 64 + chain_local;

    const GruK K0 = make_k2(w_ih, w_hh, b_ih, b_hh, L0 + 0, L0 + 1);
    const GruK K1 = make_k2(w_ih, w_hh, b_ih, b_hh, L0 + 2, L0 + 3);
    const GruK K2 = make_k2(w_ih, w_hh, b_ih, b_hh, L0 + 4, L0 + 5);

    // Stage the block's 64 chains' input sequences: xl[cl][t] = inputs[b,0,node,t]
    for (int i = tid; i < 64 * TLEN; i += 256) {
        const int cl = i / TLEN, t = i - cl * TLEN;
        const int cc = blockIdx.x * 64 + cl;
        const int node = cc >> 4, b = cc & 15;
        xl[cl][t] = inputs[((size_t)b * NODES + node) * TLEN + t];
    }
    __syncthreads();

    const int H = *horizon_p;
    const int last = H * TLEN;                        // 192 for H=8
    const int ringsrc = (lane & 60) | ((sl + 3) & 3); // prev lane in 4-ring
    const bool lead = (sl == 0);
    const float* xrow = &xl[chain_local][0];

    v2f h0 = (v2f){0.0f, 0.0f}, h1 = h0, h2 = h0;

    // Fill: ticks [0, 24). Lead lane's first slot takes the original input.
    for (int k = 0; k < TLEN; ++k) {
        float rel = __shfl(h2.y, ringsrc, 64);
        v2f in0; in0.x = lead ? xrow[k] : rel; in0.y = h0.x;
        v2f in1; in1.x = h0.y; in1.y = h1.x;
        v2f in2; in2.x = h1.y; in2.y = h2.x;
        v2f n0 = gru_cell(K0, h0, in0);
        v2f n1 = gru_cell(K1, h1, in1);
        v2f n2 = gru_cell(K2, h2, in2);
        h0.x = (k >= L0 + 0) ? n0.x : h0.x;
        h0.y = (k >= L0 + 1) ? n0.y : h0.y;
        h1.x = (k >= L0 + 2) ? n1.x : h1.x;
        h1.y = (k >= L0 + 3) ? n1.y : h1.y;
        h2.x = (k >= L0 + 4) ? n2.x : h2.x;
        h2.y = (k >= L0 + 5) ? n2.y : h2.y;
    }
    // Steady: ticks [24, last) — all slots active, no masks, ONE shfl.
    // h2 first (next tick's shfl depends on it); unroll 4 -> cross-tick SWP.
    #pragma unroll 4
    for (int k = TLEN; k < last; ++k) {
        float rel = __shfl(h2.y, ringsrc, 64);
        v2f in2; in2.x = h1.y; in2.y = h2.x;
        v2f in1; in1.x = h0.y; in1.y = h1.x;
        v2f in0; in0.x = rel;  in0.y = h0.x;
        h2 = gru_cell(K2, h2, in2);
        h1 = gru_cell(K1, h1, in1);
        h0 = gru_cell(K0, h0, in0);
    }
    // Drain: ticks [last, last+23). Layer l's final update is at k = l+last-1.
    for (int k = last; k < last + LAYERS - 1; ++k) {
        float rel = __shfl(h2.y, ringsrc, 64);
        v2f in0; in0.x = rel;  in0.y = h0.x;
        v2f in1; in1.x = h0.y; in1.y = h1.x;
        v2f in2; in2.x = h1.y; in2.y = h2.x;
        v2f n0 = gru_cell(K0, h0, in0);
        v2f n1 = gru_cell(K1, h1, in1);
        v2f n2 = gru_cell(K2, h2, in2);
        h0.x = (k < L0 + 0 + last) ? n0.x : h0.x;
        h0.y = (k < L0 + 1 + last) ? n0.y : h0.y;
        h1.x = (k < L0 + 2 + last) ? n1.x : h1.x;
        h1.y = (k < L0 + 3 + last) ? n1.y : h1.y;
        h2.x = (k < L0 + 4 + last) ? n2.x : h2.x;
        h2.y = (k < L0 + 5 + last) ? n2.y : h2.y;
    }

    // Outputs: hv[L][c] scratch and h_out[node][L][b].
    const int node = c >> 4, b = c & 15;
    float* ho = h_out + (size_t)node * (LAYERS * BATCH) + b;
    hv[(size_t)(L0 + 0) * NLANES + c] = h0.x;  ho[(L0 + 0) * BATCH] = h0.x;
    hv[(size_t)(L0 + 1) * NLANES + c] = h0.y;  ho[(L0 + 1) * BATCH] = h0.y;
    hv[(size_t)(L0 + 2) * NLANES + c] = h1.x;  ho[(L0 + 2) * BATCH] = h1.x;
    hv[(size_t)(L0 + 3) * NLANES + c] = h1.y;  ho[(L0 + 3) * BATCH] = h1.y;
    hv[(size_t)(L0 + 4) * NLANES + c] = h2.x;  ho[(L0 + 4) * BATCH] = h2.x;
    hv[(size_t)(L0 + 5) * NLANES + c] = h2.y;  ho[(L0 + 5) * BATCH] = h2.y;
}

// adj[l][i][j] = dot_b(hv[l,i,:], hv[l,j,:]) * inv_i * inv_j.
// 64x64 tile per 256-thread block; B tile transposed in LDS (conflict-free).
// At the HBM-write floor (~100 MB output).
__global__ __launch_bounds__(256) void adj_kernel(
    const float* __restrict__ hv, float* __restrict__ adj)
{
    const int l = blockIdx.z;
    const int i0 = blockIdx.y * 64;
    const int j0 = blockIdx.x * 64;
    __shared__ float As[64 * 16];   // [row][k]
    __shared__ float Bt[16 * 64];   // [k][col]
    __shared__ float iA[64];
    __shared__ float iB[64];
    const int tid = threadIdx.x;
    const float* hvl = hv + (size_t)l * NLANES;

    ((float4*)As)[tid] = ((const float4*)(hvl + (size_t)i0 * 16))[tid];
    {
        const int j = tid >> 2;
        const int kc = (tid & 3) * 4;
        float4 bv = *(const float4*)(hvl + (size_t)(j0 + j) * 16 + kc);
        Bt[(kc + 0) * 64 + j] = bv.x;
        Bt[(kc + 1) * 64 + j] = bv.y;
        Bt[(kc + 2) * 64 + j] = bv.z;
        Bt[(kc + 3) * 64 + j] = bv.w;
    }
    __syncthreads();

    if (tid < 64) {
        float s = 0.0f;
        #pragma unroll
        for (int k = 0; k < 16; ++k) { float v = As[tid * 16 + k]; s = fmaf(v, v, s); }
        iA[tid] = fast_rcp(fmaxf(sqrtf(s), 1e-8f));
    } else if (tid < 128) {
        const int j = tid - 64;
        float s = 0.0f;
        #pragma unroll
        for (int k = 0; k < 16; ++k) { float v = Bt[k * 64 + j]; s = fmaf(v, v, s); }
        iB[j] = fast_rcp(fmaxf(sqrtf(s), 1e-8f));
    }
    __syncthreads();

    const int ty = tid >> 4;   // row group (4 rows)
    const int tx = tid & 15;   // col group (4 cols = 1 float4)

    float4 acc0 = {0,0,0,0}, acc1 = {0,0,0,0}, acc2 = {0,0,0,0}, acc3 = {0,0,0,0};
    #pragma unroll
    for (int kk = 0; kk < 4; ++kk) {
        float4 a0 = ((const float4*)As)[(ty * 4 + 0) * 4 + kk];
        float4 a1 = ((const float4*)As)[(ty * 4 + 1) * 4 + kk];
        float4 a2 = ((const float4*)As)[(ty * 4 + 2) * 4 + kk];
        float4 a3 = ((const float4*)As)[(ty * 4 + 3) * 4 + kk];
        #pragma unroll
        for (int e = 0; e < 4; ++e) {
            const int k = kk * 4 + e;
            float4 bk = ((const float4*)Bt)[k * 16 + tx];
            const float a0e = (e == 0) ? a0.x : (e == 1) ? a0.y : (e == 2) ? a0.z : a0.w;
            const float a1e = (e == 0) ? a1.x : (e == 1) ? a1.y : (e == 2) ? a1.z : a1.w;
            const float a2e = (e == 0) ? a2.x : (e == 1) ? a2.y : (e == 2) ? a2.z : a2.w;
            const float a3e = (e == 0) ? a3.x : (e == 1) ? a3.y : (e == 2) ? a3.z : a3.w;
            acc0.x = fmaf(a0e, bk.x, acc0.x); acc0.y = fmaf(a0e, bk.y, acc0.y);
            acc0.z = fmaf(a0e, bk.z, acc0.z); acc0.w = fmaf(a0e, bk.w, acc0.w);
            acc1.x = fmaf(a1e, bk.x, acc1.x); acc1.y = fmaf(a1e, bk.y, acc1.y);
            acc1.z = fmaf(a1e, bk.z, acc1.z); acc1.w = fmaf(a1e, bk.w, acc1.w);
            acc2.x = fmaf(a2e, bk.x, acc2.x); acc2.y = fmaf(a2e, bk.y, acc2.y);
            acc2.z = fmaf(a2e, bk.z, acc2.z); acc2.w = fmaf(a2e, bk.w, acc2.w);
            acc3.x = fmaf(a3e, bk.x, acc3.x); acc3.y = fmaf(a3e, bk.y, acc3.y);
            acc3.z = fmaf(a3e, bk.z, acc3.z); acc3.w = fmaf(a3e, bk.w, acc3.w);
        }
    }

    float* out = adj + (size_t)l * NODES * NODES;
    const float4 ib4 = ((const float4*)iB)[tx];
    #pragma unroll
    for (int ii = 0; ii < 4; ++ii) {
        const int i = i0 + ty * 4 + ii;
        const float si = iA[ty * 4 + ii];
        float4 a = (ii == 0) ? acc0 : (ii == 1) ? acc1 : (ii == 2) ? acc2 : acc3;
        float4 w;
        w.x = a.x * si * ib4.x;
        w.y = a.y * si * ib4.y;
        w.z = a.z * si * ib4.z;
        w.w = a.w * si * ib4.w;
        *(float4*)(out + (size_t)i * NODES + j0 + tx * 4) = w;
    }
}

extern "C" void kernel_launch(void* const* d_in, const int* in_sizes, int n_in,
                              void* d_out, int out_size, void* d_ws, size_t ws_size,
                              hipStream_t stream) {
    const float* inputs = (const float*)d_in[0];
    const float* w_ih   = (const float*)d_in[1];
    const float* w_hh   = (const float*)d_in[2];
    const float* b_ih   = (const float*)d_in[3];
    const float* b_hh   = (const float*)d_in[4];
    const int*   horiz  = (const int*)d_in[5];

    float* adj   = (float*)d_out;                                   // [24,1024,1024]
    float* h_out = (float*)d_out + (size_t)LAYERS * NODES * NODES;  // [1024,24,16]
    float* hv    = (float*)d_ws;                                    // [24][16384]

    // 256 blocks x 256 threads = 1024 waves; 64 chains/block, all lanes active
    gru_pipe_kernel<<<NLANES / 64, 256, 0, stream>>>(inputs, w_ih, w_hh, b_ih, b_hh,
                                                     horiz, hv, h_out);

    dim3 grid(NODES / 64, NODES / 64, LAYERS);
    adj_kernel<<<grid, 256, 0, stream>>>(hv, adj);
}

// Round 8
// 76.947 us; speedup vs baseline: 1.1453x; 1.0514x over previous
//
#include <hip/hip_runtime.h>
#include <math.h>

#define NODES 1024
#define BATCH 16
#define TLEN 24
#define LAYERS 24
#define NLANES (NODES * BATCH) /* 16384 */
#define LOG2E 1.44269504088896340736f

typedef float v2f __attribute__((ext_vector_type(2)));

#if __has_builtin(__builtin_amdgcn_rcpf)
__device__ __forceinline__ float fast_rcp(float x) { return __builtin_amdgcn_rcpf(x); }
#else
__device__ __forceinline__ float fast_rcp(float x) { return 1.0f / x; }
#endif

#if __has_builtin(__builtin_amdgcn_exp2f)
__device__ __forceinline__ float fast_exp2(float x) { return __builtin_amdgcn_exp2f(x); }
#else
__device__ __forceinline__ float fast_exp2(float x) { return exp2f(x); }
#endif

// Packed math via COMPILER vector ops (no inline asm) -> v_pk_* on gfx950.
#if __has_builtin(__builtin_elementwise_fma)
__device__ __forceinline__ v2f pk_fma(v2f a, v2f b, v2f c) {
    return __builtin_elementwise_fma(a, b, c);
}
#else
__device__ __forceinline__ v2f pk_fma(v2f a, v2f b, v2f c) {
    v2f d; d.x = fmaf(a.x, b.x, c.x); d.y = fmaf(a.y, b.y, c.y); return d;
}
#endif

struct GruK2 { v2f rW, rU, rC, zW, zU, zC, nW, nC, nU, nD; };
struct GruKs { float rW, rU, rC, zW, zU, zC, nW, nC, nU, nD; };

// Constants for TWO layers (la -> .x, lb -> .y), pre-scaled by -log2e.
__device__ __forceinline__ GruK2 make_k2(
    const float* __restrict__ w_ih, const float* __restrict__ w_hh,
    const float* __restrict__ b_ih, const float* __restrict__ b_hh,
    int la, int lb)
{
    GruK2 K;
    #pragma unroll
    for (int s = 0; s < 2; ++s) {
        const int l = s ? lb : la;
        K.rW[s] = -LOG2E * w_ih[l*3+0]; K.rU[s] = -LOG2E * w_hh[l*3+0];
        K.rC[s] = -LOG2E * (b_ih[l*3+0] + b_hh[l*3+0]);
        K.zW[s] = -LOG2E * w_ih[l*3+1]; K.zU[s] = -LOG2E * w_hh[l*3+1];
        K.zC[s] = -LOG2E * (b_ih[l*3+1] + b_hh[l*3+1]);
        K.nW[s] = -2.0f*LOG2E * w_ih[l*3+2]; K.nC[s] = -2.0f*LOG2E * b_ih[l*3+2];
        K.nU[s] = -2.0f*LOG2E * w_hh[l*3+2]; K.nD[s] = -2.0f*LOG2E * b_hh[l*3+2];
    }
    return K;
}

__device__ __forceinline__ GruKs make_ks(
    const float* __restrict__ w_ih, const float* __restrict__ w_hh,
    const float* __restrict__ b_ih, const float* __restrict__ b_hh, int l)
{
    GruKs K;
    K.rW = -LOG2E * w_ih[l*3+0]; K.rU = -LOG2E * w_hh[l*3+0];
    K.rC = -LOG2E * (b_ih[l*3+0] + b_hh[l*3+0]);
    K.zW = -LOG2E * w_ih[l*3+1]; K.zU = -LOG2E * w_hh[l*3+1];
    K.zC = -LOG2E * (b_ih[l*3+1] + b_hh[l*3+1]);
    K.nW = -2.0f*LOG2E * w_ih[l*3+2]; K.nC = -2.0f*LOG2E * b_ih[l*3+2];
    K.nU = -2.0f*LOG2E * w_hh[l*3+2]; K.nD = -2.0f*LOG2E * b_hh[l*3+2];
    return K;
}

// GRU cell, v2f (2 layer-slots) — arithmetic bit-identical to rounds 4-7:
// er/ez/en are e^{-a} forms; r = 1/(1+er);
// h' = (ez*(1-en) + h*(1+en)) / ((1+ez)*(1+en))  -- one final rcp.
__device__ __forceinline__ v2f gru_cell2(const GruK2& K, v2f h, v2f xin) {
    const v2f ONE = (v2f){1.0f, 1.0f};
    v2f ar = pk_fma(K.rU, h, pk_fma(K.rW, xin, K.rC));
    v2f az = pk_fma(K.zU, h, pk_fma(K.zW, xin, K.zC));
    v2f er; er.x = fast_exp2(ar.x); er.y = fast_exp2(ar.y);
    v2f ez; ez.x = fast_exp2(az.x); ez.y = fast_exp2(az.y);
    v2f er1 = er + ONE;
    v2f r;  r.x = fast_rcp(er1.x); r.y = fast_rcp(er1.y);
    v2f an = pk_fma(r, pk_fma(K.nU, h, K.nD), pk_fma(K.nW, xin, K.nC));
    v2f en; en.x = fast_exp2(an.x); en.y = fast_exp2(an.y);
    v2f num = pk_fma(en, h - ez, h + ez);
    v2f den = (ez + ONE) * (en + ONE);
    v2f rd; rd.x = fast_rcp(den.x); rd.y = fast_rcp(den.y);
    return num * rd;
}

// Scalar GRU cell — per-component identical to gru_cell2.
__device__ __forceinline__ float gru_cells(const GruKs& K, float h, float xin) {
    float ar = fmaf(K.rU, h, fmaf(K.rW, xin, K.rC));
    float az = fmaf(K.zU, h, fmaf(K.zW, xin, K.zC));
    float er = fast_exp2(ar);
    float ez = fast_exp2(az);
    float r  = fast_rcp(1.0f + er);
    float an = fmaf(r, fmaf(K.nU, h, K.nD), fmaf(K.nW, xin, K.nC));
    float en = fast_exp2(an);
    float num = fmaf(en, h - ez, h + ez);
    float den = (1.0f + ez) * (1.0f + en);
    return num * fast_rcp(den);
}

// Ring-pipelined GRU: 8-lane rings, 3 CONSECUTIVE layers per lane, ONE chain
// per lane. Lane sl owns layers 3sl (h01.x), 3sl+1 (h01.y), 3sl+2 (h2).
// Cell (p,l,t) at tick p*24+l+t. Prev-tick inputs:
//   h01.x <- prev lane's h2 (ONE shfl; pass-wrap 0<-23 is the same shfl),
//   h01.y <- own h01.x,   h2 <- own h01.y      (registers).
// Layers (3sl,3sl+1) computed as one packed v2f cell, 3sl+2 scalar.
// Wave64 = 8 rings, all lanes active: 8 chains/wave, ILP 3.
// 2048 waves = 2 waves/SIMD (the round-7 fix: 6 streams per SIMD).
__global__ __launch_bounds__(256) void gru_pipe_kernel(
    const float* __restrict__ inputs, const float* __restrict__ w_ih,
    const float* __restrict__ w_hh, const float* __restrict__ b_ih,
    const float* __restrict__ b_hh, const int* __restrict__ horizon_p,
    float* __restrict__ hv, float* __restrict__ h_out)
{
    __shared__ float xl[32][TLEN + 1];   // 32 chains/block, +1 pad
    const int tid = threadIdx.x;
    const int wid = tid >> 6;
    const int lane = tid & 63;
    const int ring = lane >> 3;          // 0..7
    const int sl = lane & 7;             // ring-local lane
    const int L0 = 3 * sl;               // first owned layer
    const int chain_local = wid * 8 + ring;
    const int c = blockIdx.x * 32 + chain_local;

    const GruK2 K01 = make_k2(w_ih, w_hh, b_ih, b_hh, L0, L0 + 1);
    const GruKs K2  = make_ks(w_ih, w_hh, b_ih, b_hh, L0 + 2);

    // Stage the block's 32 chains' input sequences: xl[cl][t] = inputs[b,0,node,t]
    for (int i = tid; i < 32 * TLEN; i += 256) {
        const int cl = i / TLEN, t = i - cl * TLEN;
        const int cc = blockIdx.x * 32 + cl;
        const int node = cc >> 4, b = cc & 15;
        xl[cl][t] = inputs[((size_t)b * NODES + node) * TLEN + t];
    }
    __syncthreads();

    const int H = *horizon_p;
    const int last = H * TLEN;                        // 192 for H=8
    const int ringsrc = (lane & 56) | ((sl + 7) & 7); // prev lane in 8-ring
    const bool lead = (sl == 0);
    const float* xrow = &xl[chain_local][0];

    v2f h01 = (v2f){0.0f, 0.0f};
    float h2 = 0.0f;

    // Fill: ticks [0, 24). Lead lane's first slot takes the original input.
    for (int k = 0; k < TLEN; ++k) {
        float rel = __shfl(h2, ringsrc, 64);
        v2f in01; in01.x = lead ? xrow[k] : rel; in01.y = h01.x;
        float p1 = h01.y;
        v2f n01 = gru_cell2(K01, h01, in01);
        float n2 = gru_cells(K2, h2, p1);
        h01.x = (k >= L0 + 0) ? n01.x : h01.x;
        h01.y = (k >= L0 + 1) ? n01.y : h01.y;
        h2    = (k >= L0 + 2) ? n2   : h2;
    }
    // Steady: ticks [24, last) — all slots active, no masks, ONE shfl.
    #pragma unroll 4
    for (int k = TLEN; k < last; ++k) {
        float rel = __shfl(h2, ringsrc, 64);
        float p1 = h01.y;
        v2f in01; in01.x = rel; in01.y = h01.x;
        h2  = gru_cells(K2, h2, p1);          // uses pre-update h01.y
        h01 = gru_cell2(K01, h01, in01);
    }
    // Drain: ticks [last, last+23). Layer l's last update is tick l+last-1.
    for (int k = last; k < last + LAYERS - 1; ++k) {
        float rel = __shfl(h2, ringsrc, 64);
        v2f in01; in01.x = rel; in01.y = h01.x;
        float p1 = h01.y;
        v2f n01 = gru_cell2(K01, h01, in01);
        float n2 = gru_cells(K2, h2, p1);
        h01.x = (k < L0 + 0 + last) ? n01.x : h01.x;
        h01.y = (k < L0 + 1 + last) ? n01.y : h01.y;
        h2    = (k < L0 + 2 + last) ? n2   : h2;
    }

    // Outputs: hv[L][c] scratch and h_out[node][L][b].
    const int node = c >> 4, b = c & 15;
    float* ho = h_out + (size_t)node * (LAYERS * BATCH) + b;
    hv[(size_t)(L0 + 0) * NLANES + c] = h01.x;  ho[(L0 + 0) * BATCH] = h01.x;
    hv[(size_t)(L0 + 1) * NLANES + c] = h01.y;  ho[(L0 + 1) * BATCH] = h01.y;
    hv[(size_t)(L0 + 2) * NLANES + c] = h2;     ho[(L0 + 2) * BATCH] = h2;
}

// adj[l][i][j] = dot_b(hv[l,i,:], hv[l,j,:]) * inv_i * inv_j.
// 64x64 tile per 256-thread block; B tile transposed in LDS (conflict-free).
// At the HBM-write floor (~100 MB output, ~16 us).
__global__ __launch_bounds__(256) void adj_kernel(
    const float* __restrict__ hv, float* __restrict__ adj)
{
    const int l = blockIdx.z;
    const int i0 = blockIdx.y * 64;
    const int j0 = blockIdx.x * 64;
    __shared__ float As[64 * 16];   // [row][k]
    __shared__ float Bt[16 * 64];   // [k][col]
    __shared__ float iA[64];
    __shared__ float iB[64];
    const int tid = threadIdx.x;
    const float* hvl = hv + (size_t)l * NLANES;

    ((float4*)As)[tid] = ((const float4*)(hvl + (size_t)i0 * 16))[tid];
    {
        const int j = tid >> 2;
        const int kc = (tid & 3) * 4;
        float4 bv = *(const float4*)(hvl + (size_t)(j0 + j) * 16 + kc);
        Bt[(kc + 0) * 64 + j] = bv.x;
        Bt[(kc + 1) * 64 + j] = bv.y;
        Bt[(kc + 2) * 64 + j] = bv.z;
        Bt[(kc + 3) * 64 + j] = bv.w;
    }
    __syncthreads();

    if (tid < 64) {
        float s = 0.0f;
        #pragma unroll
        for (int k = 0; k < 16; ++k) { float v = As[tid * 16 + k]; s = fmaf(v, v, s); }
        iA[tid] = fast_rcp(fmaxf(sqrtf(s), 1e-8f));
    } else if (tid < 128) {
        const int j = tid - 64;
        float s = 0.0f;
        #pragma unroll
        for (int k = 0; k < 16; ++k) { float v = Bt[k * 64 + j]; s = fmaf(v, v, s); }
        iB[j] = fast_rcp(fmaxf(sqrtf(s), 1e-8f));
    }
    __syncthreads();

    const int ty = tid >> 4;   // row group (4 rows)
    const int tx = tid & 15;   // col group (4 cols = 1 float4)

    float4 acc0 = {0,0,0,0}, acc1 = {0,0,0,0}, acc2 = {0,0,0,0}, acc3 = {0,0,0,0};
    #pragma unroll
    for (int kk = 0; kk < 4; ++kk) {
        float4 a0 = ((const float4*)As)[(ty * 4 + 0) * 4 + kk];
        float4 a1 = ((const float4*)As)[(ty * 4 + 1) * 4 + kk];
        float4 a2 = ((const float4*)As)[(ty * 4 + 2) * 4 + kk];
        float4 a3 = ((const float4*)As)[(ty * 4 + 3) * 4 + kk];
        #pragma unroll
        for (int e = 0; e < 4; ++e) {
            const int k = kk * 4 + e;
            float4 bk = ((const float4*)Bt)[k * 16 + tx];
            const float a0e = (e == 0) ? a0.x : (e == 1) ? a0.y : (e == 2) ? a0.z : a0.w;
            const float a1e = (e == 0) ? a1.x : (e == 1) ? a1.y : (e == 2) ? a1.z : a1.w;
            const float a2e = (e == 0) ? a2.x : (e == 1) ? a2.y : (e == 2) ? a2.z : a2.w;
            const float a3e = (e == 0) ? a3.x : (e == 1) ? a3.y : (e == 2) ? a3.z : a3.w;
            acc0.x = fmaf(a0e, bk.x, acc0.x); acc0.y = fmaf(a0e, bk.y, acc0.y);
            acc0.z = fmaf(a0e, bk.z, acc0.z); acc0.w = fmaf(a0e, bk.w, acc0.w);
            acc1.x = fmaf(a1e, bk.x, acc1.x); acc1.y = fmaf(a1e, bk.y, acc1.y);
            acc1.z = fmaf(a1e, bk.z, acc1.z); acc1.w = fmaf(a1e, bk.w, acc1.w);
            acc2.x = fmaf(a2e, bk.x, acc2.x); acc2.y = fmaf(a2e, bk.y, acc2.y);
            acc2.z = fmaf(a2e, bk.z, acc2.z); acc2.w = fmaf(a2e, bk.w, acc2.w);
            acc3.x = fmaf(a3e, bk.x, acc3.x); acc3.y = fmaf(a3e, bk.y, acc3.y);
            acc3.z = fmaf(a3e, bk.z, acc3.z); acc3.w = fmaf(a3e, bk.w, acc3.w);
        }
    }

    float* out = adj + (size_t)l * NODES * NODES;
    const float4 ib4 = ((const float4*)iB)[tx];
    #pragma unroll
    for (int ii = 0; ii < 4; ++ii) {
        const int i = i0 + ty * 4 + ii;
        const float si = iA[ty * 4 + ii];
        float4 a = (ii == 0) ? acc0 : (ii == 1) ? acc1 : (ii == 2) ? acc2 : acc3;
        float4 w;
        w.x = a.x * si * ib4.x;
        w.y = a.y * si * ib4.y;
        w.z = a.z * si * ib4.z;
        w.w = a.w * si * ib4.w;
        *(float4*)(out + (size_t)i * NODES + j0 + tx * 4) = w;
    }
}

extern "C" void kernel_launch(void* const* d_in, const int* in_sizes, int n_in,
                              void* d_out, int out_size, void* d_ws, size_t ws_size,
                              hipStream_t stream) {
    const float* inputs = (const float*)d_in[0];
    const float* w_ih   = (const float*)d_in[1];
    const float* w_hh   = (const float*)d_in[2];
    const float* b_ih   = (const float*)d_in[3];
    const float* b_hh   = (const float*)d_in[4];
    const int*   horiz  = (const int*)d_in[5];

    float* adj   = (float*)d_out;                                   // [24,1024,1024]
    float* h_out = (float*)d_out + (size_t)LAYERS * NODES * NODES;  // [1024,24,16]
    float* hv    = (float*)d_ws;                                    // [24][16384]

    // 512 blocks x 256 threads = 2048 waves = 2/SIMD; 32 chains/block
    gru_pipe_kernel<<<NLANES / 32, 256, 0, stream>>>(inputs, w_ih, w_hh, b_ih, b_hh,
                                                     horiz, hv, h_out);

    dim3 grid(NODES / 64, NODES / 64, LAYERS);
    adj_kernel<<<grid, 256, 0, stream>>>(hv, adj);
}

// Round 9
// 75.413 us; speedup vs baseline: 1.1685x; 1.0203x over previous
//
#include <hip/hip_runtime.h>
#include <math.h>

#define NODES 1024
#define BATCH 16
#define TLEN 24
#define LAYERS 24
#define NLANES (NODES * BATCH) /* 16384 */
#define LOG2E 1.44269504088896340736f

typedef float v2f __attribute__((ext_vector_type(2)));

#if __has_builtin(__builtin_amdgcn_rcpf)
__device__ __forceinline__ float fast_rcp(float x) { return __builtin_amdgcn_rcpf(x); }
#else
__device__ __forceinline__ float fast_rcp(float x) { return 1.0f / x; }
#endif

#if __has_builtin(__builtin_amdgcn_exp2f)
__device__ __forceinline__ float fast_exp2(float x) { return __builtin_amdgcn_exp2f(x); }
#else
__device__ __forceinline__ float fast_exp2(float x) { return exp2f(x); }
#endif

// Packed math via COMPILER vector ops (no inline asm) -> v_pk_* on gfx950.
#if __has_builtin(__builtin_elementwise_fma)
__device__ __forceinline__ v2f pk_fma(v2f a, v2f b, v2f c) {
    return __builtin_elementwise_fma(a, b, c);
}
#else
__device__ __forceinline__ v2f pk_fma(v2f a, v2f b, v2f c) {
    v2f d; d.x = fmaf(a.x, b.x, c.x); d.y = fmaf(a.y, b.y, c.y); return d;
}
#endif

struct GruK2 { v2f rW, rU, rC, zW, zU, zC, nW, nC, nU, nD; };
struct GruKs { float rW, rU, rC, zW, zU, zC, nW, nC, nU, nD; };

// Constants for TWO layers (la -> .x, lb -> .y), pre-scaled by -log2e.
__device__ __forceinline__ GruK2 make_k2(
    const float* __restrict__ w_ih, const float* __restrict__ w_hh,
    const float* __restrict__ b_ih, const float* __restrict__ b_hh,
    int la, int lb)
{
    GruK2 K;
    #pragma unroll
    for (int s = 0; s < 2; ++s) {
        const int l = s ? lb : la;
        K.rW[s] = -LOG2E * w_ih[l*3+0]; K.rU[s] = -LOG2E * w_hh[l*3+0];
        K.rC[s] = -LOG2E * (b_ih[l*3+0] + b_hh[l*3+0]);
        K.zW[s] = -LOG2E * w_ih[l*3+1]; K.zU[s] = -LOG2E * w_hh[l*3+1];
        K.zC[s] = -LOG2E * (b_ih[l*3+1] + b_hh[l*3+1]);
        K.nW[s] = -2.0f*LOG2E * w_ih[l*3+2]; K.nC[s] = -2.0f*LOG2E * b_ih[l*3+2];
        K.nU[s] = -2.0f*LOG2E * w_hh[l*3+2]; K.nD[s] = -2.0f*LOG2E * b_hh[l*3+2];
    }
    return K;
}

__device__ __forceinline__ GruKs make_ks(
    const float* __restrict__ w_ih, const float* __restrict__ w_hh,
    const float* __restrict__ b_ih, const float* __restrict__ b_hh, int l)
{
    GruKs K;
    K.rW = -LOG2E * w_ih[l*3+0]; K.rU = -LOG2E * w_hh[l*3+0];
    K.rC = -LOG2E * (b_ih[l*3+0] + b_hh[l*3+0]);
    K.zW = -LOG2E * w_ih[l*3+1]; K.zU = -LOG2E * w_hh[l*3+1];
    K.zC = -LOG2E * (b_ih[l*3+1] + b_hh[l*3+1]);
    K.nW = -2.0f*LOG2E * w_ih[l*3+2]; K.nC = -2.0f*LOG2E * b_ih[l*3+2];
    K.nU = -2.0f*LOG2E * w_hh[l*3+2]; K.nD = -2.0f*LOG2E * b_hh[l*3+2];
    return K;
}

// GRU cell, v2f (2 layer-slots) — arithmetic bit-identical to rounds 4-8:
// er/ez/en are e^{-a} forms; r = 1/(1+er);
// h' = (ez*(1-en) + h*(1+en)) / ((1+ez)*(1+en))  -- one final rcp.
__device__ __forceinline__ v2f gru_cell2(const GruK2& K, v2f h, v2f xin) {
    const v2f ONE = (v2f){1.0f, 1.0f};
    v2f ar = pk_fma(K.rU, h, pk_fma(K.rW, xin, K.rC));
    v2f az = pk_fma(K.zU, h, pk_fma(K.zW, xin, K.zC));
    v2f er; er.x = fast_exp2(ar.x); er.y = fast_exp2(ar.y);
    v2f ez; ez.x = fast_exp2(az.x); ez.y = fast_exp2(az.y);
    v2f er1 = er + ONE;
    v2f r;  r.x = fast_rcp(er1.x); r.y = fast_rcp(er1.y);
    v2f an = pk_fma(r, pk_fma(K.nU, h, K.nD), pk_fma(K.nW, xin, K.nC));
    v2f en; en.x = fast_exp2(an.x); en.y = fast_exp2(an.y);
    v2f num = pk_fma(en, h - ez, h + ez);
    v2f den = (ez + ONE) * (en + ONE);
    v2f rd; rd.x = fast_rcp(den.x); rd.y = fast_rcp(den.y);
    return num * rd;
}

// Scalar GRU cell — per-component identical to gru_cell2.
__device__ __forceinline__ float gru_cells(const GruKs& K, float h, float xin) {
    float ar = fmaf(K.rU, h, fmaf(K.rW, xin, K.rC));
    float az = fmaf(K.zU, h, fmaf(K.zW, xin, K.zC));
    float er = fast_exp2(ar);
    float ez = fast_exp2(az);
    float r  = fast_rcp(1.0f + er);
    float an = fmaf(r, fmaf(K.nU, h, K.nD), fmaf(K.nW, xin, K.nC));
    float en = fast_exp2(an);
    float num = fmaf(en, h - ez, h + ez);
    float den = (1.0f + ez) * (1.0f + en);
    return num * fast_rcp(den);
}

// Ring-pipelined GRU: 8-lane rings, 3 CONSECUTIVE layers per lane, ONE chain
// per lane (round-8 geometry: 2 waves/SIMD, ILP 3, 8-lane rings never cross
// the 32-lane half — no bpermute half-crossing conflicts).
// Round-9 change: SOFTWARE-PIPELINED ring handoff. Invariant: entering tick
// k, rel == shfl(h2 after tick k-1) (rel=0 at k=0 since h2 init = 0). Each
// body updates h2 FIRST, then issues shfl(h2) for tick k+1, THEN computes
// the ~100-cycle packed h01 cell — bpermute latency hides under h01.
__global__ __launch_bounds__(256) void gru_pipe_kernel(
    const float* __restrict__ inputs, const float* __restrict__ w_ih,
    const float* __restrict__ w_hh, const float* __restrict__ b_ih,
    const float* __restrict__ b_hh, const int* __restrict__ horizon_p,
    float* __restrict__ hv, float* __restrict__ h_out)
{
    __shared__ float xl[32][TLEN + 1];   // 32 chains/block, +1 pad
    const int tid = threadIdx.x;
    const int wid = tid >> 6;
    const int lane = tid & 63;
    const int ring = lane >> 3;          // 0..7
    const int sl = lane & 7;             // ring-local lane
    const int L0 = 3 * sl;               // first owned layer
    const int chain_local = wid * 8 + ring;
    const int c = blockIdx.x * 32 + chain_local;

    const GruK2 K01 = make_k2(w_ih, w_hh, b_ih, b_hh, L0, L0 + 1);
    const GruKs K2  = make_ks(w_ih, w_hh, b_ih, b_hh, L0 + 2);

    // Stage the block's 32 chains' input sequences: xl[cl][t] = inputs[b,0,node,t]
    for (int i = tid; i < 32 * TLEN; i += 256) {
        const int cl = i / TLEN, t = i - cl * TLEN;
        const int cc = blockIdx.x * 32 + cl;
        const int node = cc >> 4, b = cc & 15;
        xl[cl][t] = inputs[((size_t)b * NODES + node) * TLEN + t];
    }
    __syncthreads();

    const int H = *horizon_p;
    const int last = H * TLEN;                        // 192 for H=8
    const int ringsrc = (lane & 56) | ((sl + 7) & 7); // prev lane in 8-ring
    const bool lead = (sl == 0);
    const float* xrow = &xl[chain_local][0];

    v2f h01 = (v2f){0.0f, 0.0f};
    float h2 = 0.0f;
    float rel = 0.0f;   // == shfl(h2 after tick k-1); h2 init 0 -> rel 0

    // Fill: ticks [0, 24). Lead lane's first slot takes the original input.
    for (int k = 0; k < TLEN; ++k) {
        v2f in01; in01.x = lead ? xrow[k] : rel; in01.y = h01.x;
        float p1 = h01.y;
        v2f n01 = gru_cell2(K01, h01, in01);
        float n2 = gru_cells(K2, h2, p1);
        h01.x = (k >= L0 + 0) ? n01.x : h01.x;
        h01.y = (k >= L0 + 1) ? n01.y : h01.y;
        h2    = (k >= L0 + 2) ? n2   : h2;
        rel = __shfl(h2, ringsrc, 64);               // for tick k+1
    }
    // Steady: ticks [24, last) — no masks; h2 first, shfl issued early,
    // h01 (the long cell) consumes the PREVIOUS tick's rel.
    #pragma unroll 8
    for (int k = TLEN; k < last; ++k) {
        float p1 = h01.y;
        v2f in01; in01.x = rel; in01.y = h01.x;
        h2 = gru_cells(K2, h2, p1);                  // uses pre-update h01.y
        rel = __shfl(h2, ringsrc, 64);               // overlaps with h01 cell
        h01 = gru_cell2(K01, h01, in01);
    }
    // Drain: ticks [last, last+23). Layer l's last update is tick l+last-1.
    for (int k = last; k < last + LAYERS - 1; ++k) {
        v2f in01; in01.x = rel; in01.y = h01.x;
        float p1 = h01.y;
        v2f n01 = gru_cell2(K01, h01, in01);
        float n2 = gru_cells(K2, h2, p1);
        h01.x = (k < L0 + 0 + last) ? n01.x : h01.x;
        h01.y = (k < L0 + 1 + last) ? n01.y : h01.y;
        h2    = (k < L0 + 2 + last) ? n2   : h2;
        rel = __shfl(h2, ringsrc, 64);
    }

    // Outputs: hv[L][c] scratch and h_out[node][L][b].
    const int node = c >> 4, b = c & 15;
    float* ho = h_out + (size_t)node * (LAYERS * BATCH) + b;
    hv[(size_t)(L0 + 0) * NLANES + c] = h01.x;  ho[(L0 + 0) * BATCH] = h01.x;
    hv[(size_t)(L0 + 1) * NLANES + c] = h01.y;  ho[(L0 + 1) * BATCH] = h01.y;
    hv[(size_t)(L0 + 2) * NLANES + c] = h2;     ho[(L0 + 2) * BATCH] = h2;
}

// adj[l][i][j] = dot_b(hv[l,i,:], hv[l,j,:]) * inv_i * inv_j.
// 64x64 tile per 256-thread block; B tile transposed in LDS (conflict-free).
// At the HBM-write floor (~100 MB output at ~6.2 TB/s, ~16 us).
__global__ __launch_bounds__(256) void adj_kernel(
    const float* __restrict__ hv, float* __restrict__ adj)
{
    const int l = blockIdx.z;
    const int i0 = blockIdx.y * 64;
    const int j0 = blockIdx.x * 64;
    __shared__ float As[64 * 16];   // [row][k]
    __shared__ float Bt[16 * 64];   // [k][col]
    __shared__ float iA[64];
    __shared__ float iB[64];
    const int tid = threadIdx.x;
    const float* hvl = hv + (size_t)l * NLANES;

    ((float4*)As)[tid] = ((const float4*)(hvl + (size_t)i0 * 16))[tid];
    {
        const int j = tid >> 2;
        const int kc = (tid & 3) * 4;
        float4 bv = *(const float4*)(hvl + (size_t)(j0 + j) * 16 + kc);
        Bt[(kc + 0) * 64 + j] = bv.x;
        Bt[(kc + 1) * 64 + j] = bv.y;
        Bt[(kc + 2) * 64 + j] = bv.z;
        Bt[(kc + 3) * 64 + j] = bv.w;
    }
    __syncthreads();

    if (tid < 64) {
        float s = 0.0f;
        #pragma unroll
        for (int k = 0; k < 16; ++k) { float v = As[tid * 16 + k]; s = fmaf(v, v, s); }
        iA[tid] = fast_rcp(fmaxf(sqrtf(s), 1e-8f));
    } else if (tid < 128) {
        const int j = tid - 64;
        float s = 0.0f;
        #pragma unroll
        for (int k = 0; k < 16; ++k) { float v = Bt[k * 64 + j]; s = fmaf(v, v, s); }
        iB[j] = fast_rcp(fmaxf(sqrtf(s), 1e-8f));
    }
    __syncthreads();

    const int ty = tid >> 4;   // row group (4 rows)
    const int tx = tid & 15;   // col group (4 cols = 1 float4)

    float4 acc0 = {0,0,0,0}, acc1 = {0,0,0,0}, acc2 = {0,0,0,0}, acc3 = {0,0,0,0};
    #pragma unroll
    for (int kk = 0; kk < 4; ++kk) {
        float4 a0 = ((const float4*)As)[(ty * 4 + 0) * 4 + kk];
        float4 a1 = ((const float4*)As)[(ty * 4 + 1) * 4 + kk];
        float4 a2 = ((const float4*)As)[(ty * 4 + 2) * 4 + kk];
        float4 a3 = ((const float4*)As)[(ty * 4 + 3) * 4 + kk];
        #pragma unroll
        for (int e = 0; e < 4; ++e) {
            const int k = kk * 4 + e;
            float4 bk = ((const float4*)Bt)[k * 16 + tx];
            const float a0e = (e == 0) ? a0.x : (e == 1) ? a0.y : (e == 2) ? a0.z : a0.w;
            const float a1e = (e == 0) ? a1.x : (e == 1) ? a1.y : (e == 2) ? a1.z : a1.w;
            const float a2e = (e == 0) ? a2.x : (e == 1) ? a2.y : (e == 2) ? a2.z : a2.w;
            const float a3e = (e == 0) ? a3.x : (e == 1) ? a3.y : (e == 2) ? a3.z : a3.w;
            acc0.x = fmaf(a0e, bk.x, acc0.x); acc0.y = fmaf(a0e, bk.y, acc0.y);
            acc0.z = fmaf(a0e, bk.z, acc0.z); acc0.w = fmaf(a0e, bk.w, acc0.w);
            acc1.x = fmaf(a1e, bk.x, acc1.x); acc1.y = fmaf(a1e, bk.y, acc1.y);
            acc1.z = fmaf(a1e, bk.z, acc1.z); acc1.w = fmaf(a1e, bk.w, acc1.w);
            acc2.x = fmaf(a2e, bk.x, acc2.x); acc2.y = fmaf(a2e, bk.y, acc2.y);
            acc2.z = fmaf(a2e, bk.z, acc2.z); acc2.w = fmaf(a2e, bk.w, acc2.w);
            acc3.x = fmaf(a3e, bk.x, acc3.x); acc3.y = fmaf(a3e, bk.y, acc3.y);
            acc3.z = fmaf(a3e, bk.z, acc3.z); acc3.w = fmaf(a3e, bk.w, acc3.w);
        }
    }

    float* out = adj + (size_t)l * NODES * NODES;
    const float4 ib4 = ((const float4*)iB)[tx];
    #pragma unroll
    for (int ii = 0; ii < 4; ++ii) {
        const int i = i0 + ty * 4 + ii;
        const float si = iA[ty * 4 + ii];
        float4 a = (ii == 0) ? acc0 : (ii == 1) ? acc1 : (ii == 2) ? acc2 : acc3;
        float4 w;
        w.x = a.x * si * ib4.x;
        w.y = a.y * si * ib4.y;
        w.z = a.z * si * ib4.z;
        w.w = a.w * si * ib4.w;
        *(float4*)(out + (size_t)i * NODES + j0 + tx * 4) = w;
    }
}

extern "C" void kernel_launch(void* const* d_in, const int* in_sizes, int n_in,
                              void* d_out, int out_size, void* d_ws, size_t ws_size,
                              hipStream_t stream) {
    const float* inputs = (const float*)d_in[0];
    const float* w_ih   = (const float*)d_in[1];
    const float* w_hh   = (const float*)d_in[2];
    const float* b_ih   = (const float*)d_in[3];
    const float* b_hh   = (const float*)d_in[4];
    const int*   horiz  = (const int*)d_in[5];

    float* adj   = (float*)d_out;                                   // [24,1024,1024]
    float* h_out = (float*)d_out + (size_t)LAYERS * NODES * NODES;  // [1024,24,16]
    float* hv    = (float*)d_ws;                                    // [24][16384]

    // 512 blocks x 256 threads = 2048 waves = 2/SIMD; 32 chains/block
    gru_pipe_kernel<<<NLANES / 32, 256, 0, stream>>>(inputs, w_ih, w_hh, b_ih, b_hh,
                                                     horiz, hv, h_out);

    dim3 grid(NODES / 64, NODES / 64, LAYERS);
    adj_kernel<<<grid, 256, 0, stream>>>(hv, adj);
}